// Round 1
// baseline (181.084 us; speedup 1.0000x reference)
//
#include <hip/hip_runtime.h>
#include <cstdint>

#define R_SPHEREf 3.0f
#define NEARf 0.0f
#define FARf 100.0f
#define SECANT_STEPS 4
#define EPSf 1e-4f
#define R0f 1.0f
#define Hh 64
#define Lc 4
#define Sn 64

__global__ __launch_bounds__(256) void manifold_render_kernel(
    const float* __restrict__ rays_o, const float* __restrict__ rays_d,
    const float* __restrict__ levels, const float* __restrict__ W1,
    const float* __restrict__ b1, const float* __restrict__ W2,
    const float* __restrict__ b2, float* __restrict__ out, int N)
{
    __shared__ float4 w14[Hh];   // {W1[0][h], W1[1][h], W1[2][h], b1[h]}
    __shared__ float  w2s[Hh];

    const int tid = threadIdx.x;
    if (tid < Hh) {
        w14[tid] = make_float4(W1[tid], W1[Hh + tid], W1[2 * Hh + tid], b1[tid]);
        w2s[tid] = W2[tid];
    }
    __syncthreads();

    const int wave = tid >> 6;
    const int lane = tid & 63;
    const int r = blockIdx.x * 4 + wave;
    if (r >= N) return;

    const float b2v = b2[0];
    float lvl[Lc];
#pragma unroll
    for (int j = 0; j < Lc; ++j) lvl[j] = levels[j];

    const float ox = rays_o[3 * r], oy = rays_o[3 * r + 1], oz = rays_o[3 * r + 2];
    const float dx = rays_d[3 * r], dy = rays_d[3 * r + 1], dz = rays_d[3 * r + 2];

    // sphere bounds
    const float bq = ox * dx + oy * dy + oz * dz;
    const float cq = ox * ox + oy * oy + oz * oz - R_SPHEREf * R_SPHEREf;
    const float disc = bq * bq - cq;
    const bool hit = disc > 0.0f;
    const float sq = sqrtf(hit ? disc : 1.0f);
    const float d_near = fmaxf(-bq - sq, NEARf);
    const float d_far  = fminf(-bq + sq, FARf);
    const bool mask_bound = hit && (d_near < d_far);

    // ---- stage 2: lane = sample index; full MLP per lane ----
    const float t = (float)lane / (float)(Sn - 1);
    const float dsv = d_near * (1.0f - t) + d_far * t;
    const float x0 = ox + dx * dsv, x1 = oy + dy * dsv, x2 = oz + dz * dsv;
    const float nrm = sqrtf(x0 * x0 + x1 * x1 + x2 * x2);
    float acc = 0.0f;
#pragma unroll 4
    for (int h = 0; h < Hh; ++h) {
        float4 c = w14[h];
        float pre = x0 * c.x + x1 * c.y + x2 * c.z + c.w;
        acc += tanhf(pre) * w2s[h];
    }
    const float scal = acc + b2v + (R0f - nrm);
    const bool valid = nrm < R_SPHEREf;

    // neighbors (back sample of interval at lane j is sample j+1)
    const float scb = __shfl_down(scal, 1);
    const int validn = __shfl_down((int)valid, 1);
    const bool is_int = lane < (Sn - 1);

    // ind_lowest: first-occurrence argmin of sc_b over intervals
    float keyv = is_int ? scb : INFINITY;
    int keyi = lane;
#pragma unroll
    for (int m = 1; m < 64; m <<= 1) {
        float ov = __shfl_xor(keyv, m);
        int oi = __shfl_xor(keyi, m);
        if (ov < keyv || (ov == keyv && oi < keyi)) { keyv = ov; keyi = oi; }
    }
    const int ind_lowest = keyi;

    const bool inint_base = is_int && valid && (validn != 0);

    // per-level interval pick + secant init (uniform over all lanes)
    bool mintb[Lc], msec[Lc];
    float dinit[Lc];
    float g_dfs = 0.f, g_dbs = 0.f, g_sfs = 0.f, g_sbs = 0.f, g_dcur = 0.f, g_lr = 0.f;
    const int g = lane >> 4;

#pragma unroll
    for (int lv = 0; lv < Lc; ++lv) {
        const float l = lvl[lv];
        unsigned long long bP = __ballot(is_int && (scb < l));
        unsigned long long bZ = __ballot(is_int && (scb == l));
        unsigned long long bI = __ballot(inint_base && (scal >= l) && (l >= scb));
        // argmax of sign(l - sc_b)*(63-j): first j with sc_b<l, else first ==, else 62
        int ind_closest = bP ? __builtin_ctzll(bP)
                             : (bZ ? __builtin_ctzll(bZ) : (Sn - 2));
        bool mask_surface = (bI != 0ULL);
        int idx = mask_surface ? ind_closest : ind_lowest;

        float d_front = __shfl(dsv, idx);
        float d_back  = __shfl(dsv, idx + 1);
        float s_front = __shfl(scal, idx);
        float s_back  = __shfl(scal, idx + 1);

        bool mi = (s_front >= l) && (l >= s_back);
        float sd = s_front - s_back;
        bool vd = fabsf(sd) > EPSf;
        bool ms = mi && vd;
        float d_sec = ((l - s_back) * d_front + (s_front - l) * d_back) / (vd ? sd : 1.0f);
        float di = ms ? d_sec : d_back;

        mintb[lv] = mi; msec[lv] = ms; dinit[lv] = di;
        if (g == lv) {
            g_dfs = d_front; g_dbs = d_back; g_sfs = s_front; g_sbs = s_back;
            g_dcur = di; g_lr = l;
        }
    }

    // ---- secant refinement: 16 lanes per level, 4 hidden units per lane ----
    const int sub = lane & 15;
#pragma unroll
    for (int it = 0; it < SECANT_STEPS; ++it) {
        float mx0 = ox + g_dcur * dx, mx1 = oy + g_dcur * dy, mx2 = oz + g_dcur * dz;
        float mn = sqrtf(mx0 * mx0 + mx1 * mx1 + mx2 * mx2);
        float part = 0.0f;
#pragma unroll
        for (int k = 0; k < 4; ++k) {
            int h = sub + (k << 4);
            float4 c = w14[h];
            float pre = mx0 * c.x + mx1 * c.y + mx2 * c.z + c.w;
            part += tanhf(pre) * w2s[h];
        }
#pragma unroll
        for (int m = 1; m < 16; m <<= 1) part += __shfl_xor(part, m, 16);
        float s_mid = part + b2v + (R0f - mn);
        bool mv = mn < R_SPHEREf;
        bool upf = (s_mid > g_lr) && mv;
        bool upb = (s_mid < g_lr) && mv;
        if (upf) { g_dfs = g_dcur; g_sfs = s_mid; }
        if (upb) { g_dbs = g_dcur; g_sbs = s_mid; }
        float sd2 = g_sfs - g_sbs;
        bool ok = fabsf(sd2) > EPSf;
        if (ok) g_dcur = ((g_lr - g_sbs) * g_dfs + (g_sfs - g_lr) * g_dbs) / sd2;
    }

    // gather per-level results onto every lane
    float v0, v1, v2, v3;
    {
        float dc0 = __shfl(g_dcur, 0);
        float dc1 = __shfl(g_dcur, 16);
        float dc2 = __shfl(g_dcur, 32);
        float dc3 = __shfl(g_dcur, 48);
        v0 = msec[0] ? dc0 : dinit[0];
        v1 = msec[1] ? dc1 : dinit[1];
        v2 = msec[2] ? dc2 : dinit[2];
        v3 = msec[3] ? dc3 : dinit[3];
    }
    int m0 = mintb[0], m1 = mintb[1], m2 = mintb[2], m3 = mintb[3];
    int i0 = 0, i1 = 1, i2 = 2, i3 = 3;

    // stable sort of 4 by (value, original index) — 5-comparator network
#define CSWAP(va, ia, ma, vb, ib, mb)                                    \
    { bool sw = (vb < va) || (vb == va && ib < ia);                      \
      if (sw) { float tv = va; va = vb; vb = tv;                         \
                int ti = ia; ia = ib; ib = ti;                           \
                int tm = ma; ma = mb; mb = tm; } }
    CSWAP(v0, i0, m0, v1, i1, m1);
    CSWAP(v2, i2, m2, v3, i3, m3);
    CSWAP(v0, i0, m0, v2, i2, m2);
    CSWAP(v1, i1, m1, v3, i3, m3);
    CSWAP(v1, i1, m1, v2, i2, m2);
#undef CSWAP

    const long long NL = (long long)N * Lc;
    if (lane < Lc) {
        float dv = (lane == 0) ? v0 : (lane == 1) ? v1 : (lane == 2) ? v2 : v3;
        out[(long long)r * Lc + lane] = mask_bound ? dv : 0.0f;
    } else if (lane < 2 * Lc) {
        int k = lane - Lc;
        int mm = (k == 0) ? m0 : (k == 1) ? m1 : (k == 2) ? m2 : m3;
        out[NL + (long long)r * Lc + k] = (mm && mask_bound) ? 1.0f : 0.0f;
    }
}

extern "C" void kernel_launch(void* const* d_in, const int* in_sizes, int n_in,
                              void* d_out, int out_size, void* d_ws, size_t ws_size,
                              hipStream_t stream) {
    const float* rays_o = (const float*)d_in[0];
    const float* rays_d = (const float*)d_in[1];
    const float* levels = (const float*)d_in[2];
    const float* W1 = (const float*)d_in[3];
    const float* b1 = (const float*)d_in[4];
    const float* W2 = (const float*)d_in[5];
    const float* b2 = (const float*)d_in[6];
    float* out = (float*)d_out;

    const int N = in_sizes[0] / 3;          // B*R rays
    const int blocks = (N + 3) / 4;         // 4 waves (rays) per 256-thread block
    manifold_render_kernel<<<blocks, 256, 0, stream>>>(
        rays_o, rays_d, levels, W1, b1, W2, b2, out, N);
}

// Round 3
// 144.554 us; speedup vs baseline: 1.2527x; 1.2527x over previous
//
#include <hip/hip_runtime.h>
#include <cstdint>

#define R_SPHEREf 3.0f
#define NEARf 0.0f
#define FARf 100.0f
#define SECANT_STEPS 4
#define EPSf 1e-4f
#define R0f 1.0f
#define Hh 64
#define Lc 4
#define Sn 64

// tanh(x) = 1 - 2/(exp2(2*log2e*x) + 1), hardware v_exp_f32 + v_rcp_f32.
// hi/lo split of 2*log2e kills the constant-rounding error; one NR step on
// the rcp brings total abs error to ~2e-7. For |x| huge (only reachable when
// nrm>R_SPHERE, where the valid-mask gates all uses) may produce NaN — safe.
__device__ __forceinline__ float fast_tanh(float x) {
    const float C_HI = 2.88539004325866699f;     // float-nearest of 2*log2(e)
    const float C_LO = 3.8519227871e-08f;        // residual
    float y = __builtin_fmaf(x, C_LO, x * C_HI);
    float e = __builtin_amdgcn_exp2f(y);         // v_exp_f32
    float den = e + 1.0f;
    float r = __builtin_amdgcn_rcpf(den);        // v_rcp_f32
    r = r * __builtin_fmaf(-den, r, 2.0f);       // Newton step
    return __builtin_fmaf(-2.0f, r, 1.0f);
}

__global__ __launch_bounds__(256) void manifold_render_kernel(
    const float* __restrict__ rays_o, const float* __restrict__ rays_d,
    const float* __restrict__ levels, const float* __restrict__ W1,
    const float* __restrict__ b1, const float* __restrict__ W2,
    const float* __restrict__ b2, float* __restrict__ out, int N)
{
    __shared__ float4 w14[Hh];   // {W1[0][h], W1[1][h], W1[2][h], b1[h]}
    __shared__ float4 w2q[Hh / 4];
    __shared__ float  w2s[Hh];

    const int tid = threadIdx.x;
    if (tid < Hh) {
        w14[tid] = make_float4(W1[tid], W1[Hh + tid], W1[2 * Hh + tid], b1[tid]);
        w2s[tid] = W2[tid];
    }
    if (tid < Hh / 4) {
        w2q[tid] = make_float4(W2[4 * tid], W2[4 * tid + 1], W2[4 * tid + 2], W2[4 * tid + 3]);
    }
    __syncthreads();

    const int wave = tid >> 6;
    const int lane = tid & 63;
    const int r = blockIdx.x * 4 + wave;
    if (r >= N) return;

    const float b2v = b2[0];
    float lvl[Lc];
#pragma unroll
    for (int j = 0; j < Lc; ++j) lvl[j] = levels[j];

    const float ox = rays_o[3 * r], oy = rays_o[3 * r + 1], oz = rays_o[3 * r + 2];
    const float dx = rays_d[3 * r], dy = rays_d[3 * r + 1], dz = rays_d[3 * r + 2];

    // sphere bounds
    const float bq = ox * dx + oy * dy + oz * dz;
    const float cq = ox * ox + oy * oy + oz * oz - R_SPHEREf * R_SPHEREf;
    const float disc = bq * bq - cq;
    const bool hit = disc > 0.0f;
    const float sq = sqrtf(hit ? disc : 1.0f);
    const float d_near = fmaxf(-bq - sq, NEARf);
    const float d_far  = fminf(-bq + sq, FARf);
    const bool mask_bound = hit && (d_near < d_far);

    // ---- stage 2: lane = sample index; full MLP per lane ----
    const float t = (float)lane / (float)(Sn - 1);
    const float dsv = d_near * (1.0f - t) + d_far * t;
    const float x0 = ox + dx * dsv, x1 = oy + dy * dsv, x2 = oz + dz * dsv;
    const float nrm = sqrtf(x0 * x0 + x1 * x1 + x2 * x2);
    float acc = 0.0f;
#pragma unroll
    for (int h4 = 0; h4 < Hh / 4; ++h4) {
        const float4 wq = w2q[h4];
        float4 c;
        float pre;
        c = w14[4 * h4 + 0];
        pre = __builtin_fmaf(x0, c.x, __builtin_fmaf(x1, c.y, __builtin_fmaf(x2, c.z, c.w)));
        acc = __builtin_fmaf(fast_tanh(pre), wq.x, acc);
        c = w14[4 * h4 + 1];
        pre = __builtin_fmaf(x0, c.x, __builtin_fmaf(x1, c.y, __builtin_fmaf(x2, c.z, c.w)));
        acc = __builtin_fmaf(fast_tanh(pre), wq.y, acc);
        c = w14[4 * h4 + 2];
        pre = __builtin_fmaf(x0, c.x, __builtin_fmaf(x1, c.y, __builtin_fmaf(x2, c.z, c.w)));
        acc = __builtin_fmaf(fast_tanh(pre), wq.z, acc);
        c = w14[4 * h4 + 3];
        pre = __builtin_fmaf(x0, c.x, __builtin_fmaf(x1, c.y, __builtin_fmaf(x2, c.z, c.w)));
        acc = __builtin_fmaf(fast_tanh(pre), wq.w, acc);
    }
    const float scal = acc + b2v + (R0f - nrm);
    const bool valid = nrm < R_SPHEREf;

    // neighbors (back sample of interval at lane j is sample j+1)
    const float scb = __shfl_down(scal, 1);
    const int validn = __shfl_down((int)valid, 1);
    const bool is_int = lane < (Sn - 1);

    // ind_lowest: first-occurrence argmin of sc_b over intervals
    float keyv = is_int ? scb : INFINITY;
    int keyi = lane;
#pragma unroll
    for (int m = 1; m < 64; m <<= 1) {
        float ov = __shfl_xor(keyv, m);
        int oi = __shfl_xor(keyi, m);
        if (ov < keyv || (ov == keyv && oi < keyi)) { keyv = ov; keyi = oi; }
    }
    const int ind_lowest = keyi;

    const bool inint_base = is_int && valid && (validn != 0);

    // per-level interval pick + secant init (uniform over all lanes)
    bool mintb[Lc], msec[Lc];
    float dinit[Lc];
    float g_dfs = 0.f, g_dbs = 0.f, g_sfs = 0.f, g_sbs = 0.f, g_dcur = 0.f, g_lr = 0.f;
    const int g = lane >> 4;

#pragma unroll
    for (int lv = 0; lv < Lc; ++lv) {
        const float l = lvl[lv];
        unsigned long long bP = __ballot(is_int && (scb < l));
        unsigned long long bZ = __ballot(is_int && (scb == l));
        unsigned long long bI = __ballot(inint_base && (scal >= l) && (l >= scb));
        // argmax of sign(l - sc_b)*(63-j): first j with sc_b<l, else first ==, else 62
        int ind_closest = bP ? __builtin_ctzll(bP)
                             : (bZ ? __builtin_ctzll(bZ) : (Sn - 2));
        bool mask_surface = (bI != 0ULL);
        int idx = mask_surface ? ind_closest : ind_lowest;

        float d_front = __shfl(dsv, idx);
        float d_back  = __shfl(dsv, idx + 1);
        float s_front = __shfl(scal, idx);
        float s_back  = __shfl(scal, idx + 1);

        bool mi = (s_front >= l) && (l >= s_back);
        float sd = s_front - s_back;
        bool vd = fabsf(sd) > EPSf;
        bool ms = mi && vd;
        float d_sec = ((l - s_back) * d_front + (s_front - l) * d_back) / (vd ? sd : 1.0f);
        float di = ms ? d_sec : d_back;

        mintb[lv] = mi; msec[lv] = ms; dinit[lv] = di;
        if (g == lv) {
            g_dfs = d_front; g_dbs = d_back; g_sfs = s_front; g_sbs = s_back;
            g_dcur = di; g_lr = l;
        }
    }

    // ---- secant refinement: 16 lanes per level, 4 hidden units per lane ----
    const int sub = lane & 15;
#pragma unroll
    for (int it = 0; it < SECANT_STEPS; ++it) {
        float mx0 = ox + g_dcur * dx, mx1 = oy + g_dcur * dy, mx2 = oz + g_dcur * dz;
        float mn = sqrtf(mx0 * mx0 + mx1 * mx1 + mx2 * mx2);
        float part = 0.0f;
#pragma unroll
        for (int k = 0; k < 4; ++k) {
            int h = sub + (k << 4);
            float4 c = w14[h];
            float pre = __builtin_fmaf(mx0, c.x, __builtin_fmaf(mx1, c.y, __builtin_fmaf(mx2, c.z, c.w)));
            part = __builtin_fmaf(fast_tanh(pre), w2s[h], part);
        }
#pragma unroll
        for (int m = 1; m < 16; m <<= 1) part += __shfl_xor(part, m, 16);
        float s_mid = part + b2v + (R0f - mn);
        bool mv = mn < R_SPHEREf;
        bool upf = (s_mid > g_lr) && mv;
        bool upb = (s_mid < g_lr) && mv;
        if (upf) { g_dfs = g_dcur; g_sfs = s_mid; }
        if (upb) { g_dbs = g_dcur; g_sbs = s_mid; }
        float sd2 = g_sfs - g_sbs;
        bool ok = fabsf(sd2) > EPSf;
        if (ok) g_dcur = ((g_lr - g_sbs) * g_dfs + (g_sfs - g_lr) * g_dbs) / sd2;
    }

    // gather per-level results onto every lane
    float v0, v1, v2, v3;
    {
        float dc0 = __shfl(g_dcur, 0);
        float dc1 = __shfl(g_dcur, 16);
        float dc2 = __shfl(g_dcur, 32);
        float dc3 = __shfl(g_dcur, 48);
        v0 = msec[0] ? dc0 : dinit[0];
        v1 = msec[1] ? dc1 : dinit[1];
        v2 = msec[2] ? dc2 : dinit[2];
        v3 = msec[3] ? dc3 : dinit[3];
    }
    int m0 = mintb[0], m1 = mintb[1], m2 = mintb[2], m3 = mintb[3];
    int i0 = 0, i1 = 1, i2 = 2, i3 = 3;

    // stable sort of 4 by (value, original index) — 5-comparator network
#define CSWAP(va, ia, ma, vb, ib, mb)                                    \
    { bool sw = (vb < va) || (vb == va && ib < ia);                      \
      if (sw) { float tv = va; va = vb; vb = tv;                         \
                int ti = ia; ia = ib; ib = ti;                           \
                int tm = ma; ma = mb; mb = tm; } }
    CSWAP(v0, i0, m0, v1, i1, m1);
    CSWAP(v2, i2, m2, v3, i3, m3);
    CSWAP(v0, i0, m0, v2, i2, m2);
    CSWAP(v1, i1, m1, v3, i3, m3);
    CSWAP(v1, i1, m1, v2, i2, m2);
#undef CSWAP

    const long long NL = (long long)N * Lc;
    if (lane < Lc) {
        float dv = (lane == 0) ? v0 : (lane == 1) ? v1 : (lane == 2) ? v2 : v3;
        out[(long long)r * Lc + lane] = mask_bound ? dv : 0.0f;
    } else if (lane < 2 * Lc) {
        int k = lane - Lc;
        int mm = (k == 0) ? m0 : (k == 1) ? m1 : (k == 2) ? m2 : m3;
        out[NL + (long long)r * Lc + k] = (mm && mask_bound) ? 1.0f : 0.0f;
    }
}

extern "C" void kernel_launch(void* const* d_in, const int* in_sizes, int n_in,
                              void* d_out, int out_size, void* d_ws, size_t ws_size,
                              hipStream_t stream) {
    const float* rays_o = (const float*)d_in[0];
    const float* rays_d = (const float*)d_in[1];
    const float* levels = (const float*)d_in[2];
    const float* W1 = (const float*)d_in[3];
    const float* b1 = (const float*)d_in[4];
    const float* W2 = (const float*)d_in[5];
    const float* b2 = (const float*)d_in[6];
    float* out = (float*)d_out;

    const int N = in_sizes[0] / 3;          // B*R rays
    const int blocks = (N + 3) / 4;         // 4 waves (rays) per 256-thread block
    manifold_render_kernel<<<blocks, 256, 0, stream>>>(
        rays_o, rays_d, levels, W1, b1, W2, b2, out, N);
}

// Round 4
// 142.834 us; speedup vs baseline: 1.2678x; 1.0120x over previous
//
#include <hip/hip_runtime.h>
#include <cstdint>

#define R_SPHEREf 3.0f
#define NEARf 0.0f
#define FARf 100.0f
#define SECANT_STEPS 4
#define EPSf 1e-4f
#define R0f 1.0f
#define Hh 64
#define Lc 4
#define Sn 64

// tanh(x) = 1 - 2/(exp2(2*log2e*x) + 1), hardware v_exp_f32 + v_rcp_f32.
// hi/lo split of 2*log2e kills the constant-rounding error; one NR step on
// the rcp brings total abs error to ~2e-7. Overflow (|x| huge) only occurs
// when the valid-mask (nrm<R) gates all uses — NaN-safe by construction.
__device__ __forceinline__ float fast_tanh(float x) {
    const float C_HI = 2.88539004325866699f;     // float-nearest of 2*log2(e)
    const float C_LO = 3.8519227871e-08f;        // residual
    float y = __builtin_fmaf(x, C_LO, x * C_HI);
    float e = __builtin_amdgcn_exp2f(y);         // v_exp_f32
    float den = e + 1.0f;
    float r = __builtin_amdgcn_rcpf(den);        // v_rcp_f32
    r = r * __builtin_fmaf(-den, r, 2.0f);       // Newton step
    return __builtin_fmaf(-2.0f, r, 1.0f);
}

__global__ __launch_bounds__(256, 4) void manifold_render_kernel(
    const float* __restrict__ rays_o, const float* __restrict__ rays_d,
    const float* __restrict__ levels, const float* __restrict__ W1,
    const float* __restrict__ b1, const float* __restrict__ W2,
    const float* __restrict__ b2, float* __restrict__ out, int N)
{
    // per-wave {A_h, B_h, w2_h, 0} quads: pre_h(t) = A_h + t*B_h
    __shared__ float4 abq[4][Hh];

    const int tid = threadIdx.x;
    const int wave = tid >> 6;
    const int lane = tid & 63;
    const int r = blockIdx.x * 4 + wave;
    const bool ray_ok = (r < N);

    const float b2v = b2[0];
    float lvl[Lc];
#pragma unroll
    for (int j = 0; j < Lc; ++j) lvl[j] = levels[j];

    float ox = 0.f, oy = 0.f, oz = 0.f, dx = 0.f, dy = 0.f, dz = 1.f;
    if (ray_ok) {
        ox = rays_o[3 * r]; oy = rays_o[3 * r + 1]; oz = rays_o[3 * r + 2];
        dx = rays_d[3 * r]; dy = rays_d[3 * r + 1]; dz = rays_d[3 * r + 2];
    }

    // per-ray linearization: each lane handles h = lane (coalesced weight loads)
    {
        const float w1x = W1[lane], w1y = W1[Hh + lane], w1z = W1[2 * Hh + lane];
        const float Ah = __builtin_fmaf(oz, w1z, __builtin_fmaf(oy, w1y,
                         __builtin_fmaf(ox, w1x, b1[lane])));
        const float Bh = __builtin_fmaf(dz, w1z, __builtin_fmaf(dy, w1y, dx * w1x));
        abq[wave][lane] = make_float4(Ah, Bh, W2[lane], 0.0f);
    }
    __syncthreads();
    if (!ray_ok) return;

    // sphere bounds
    const float bq = ox * dx + oy * dy + oz * dz;
    const float cq = ox * ox + oy * oy + oz * oz - R_SPHEREf * R_SPHEREf;
    const float disc = bq * bq - cq;
    const bool hit = disc > 0.0f;
    const float sq = sqrtf(hit ? disc : 1.0f);
    const float d_near = fmaxf(-bq - sq, NEARf);
    const float d_far  = fminf(-bq + sq, FARf);
    const bool mask_bound = hit && (d_near < d_far);

    // ---- sampling: lane = sample index; 8-deep prefetched MLP ----
    const float t = (float)lane / (float)(Sn - 1);
    const float dsv = d_near * (1.0f - t) + d_far * t;
    const float x0 = ox + dx * dsv, x1 = oy + dy * dsv, x2 = oz + dz * dsv;
    const float nrm = sqrtf(x0 * x0 + x1 * x1 + x2 * x2);

    const float4* __restrict__ ab = &abq[wave][0];
    float acc = 0.0f;
#pragma unroll
    for (int blk = 0; blk < Hh / 8; ++blk) {
        float4 q[8];
#pragma unroll
        for (int j = 0; j < 8; ++j) q[j] = ab[8 * blk + j];
#pragma unroll
        for (int j = 0; j < 8; ++j) {
            float pre = __builtin_fmaf(dsv, q[j].y, q[j].x);
            acc = __builtin_fmaf(fast_tanh(pre), q[j].z, acc);
        }
    }
    const float scal = acc + b2v + (R0f - nrm);
    const bool valid = nrm < R_SPHEREf;

    // neighbors (back sample of interval at lane j is sample j+1)
    const float scb = __shfl_down(scal, 1);
    const int validn = __shfl_down((int)valid, 1);
    const bool is_int = lane < (Sn - 1);

    // ind_lowest: first-occurrence argmin of sc_b over intervals
    float keyv = is_int ? scb : INFINITY;
    int keyi = lane;
#pragma unroll
    for (int m = 1; m < 64; m <<= 1) {
        float ov = __shfl_xor(keyv, m);
        int oi = __shfl_xor(keyi, m);
        if (ov < keyv || (ov == keyv && oi < keyi)) { keyv = ov; keyi = oi; }
    }
    const int ind_lowest = keyi;

    const bool inint_base = is_int && valid && (validn != 0);

    // per-level interval pick + secant init (uniform over all lanes)
    bool mintb[Lc], msec[Lc];
    float dinit[Lc];
    float g_dfs = 0.f, g_dbs = 0.f, g_sfs = 0.f, g_sbs = 0.f, g_dcur = 0.f, g_lr = 0.f;
    const int g = lane >> 4;

#pragma unroll
    for (int lv = 0; lv < Lc; ++lv) {
        const float l = lvl[lv];
        unsigned long long bP = __ballot(is_int && (scb < l));
        unsigned long long bZ = __ballot(is_int && (scb == l));
        unsigned long long bI = __ballot(inint_base && (scal >= l) && (l >= scb));
        // argmax of sign(l - sc_b)*(63-j): first j with sc_b<l, else first ==, else 62
        int ind_closest = bP ? __builtin_ctzll(bP)
                             : (bZ ? __builtin_ctzll(bZ) : (Sn - 2));
        bool mask_surface = (bI != 0ULL);
        int idx = mask_surface ? ind_closest : ind_lowest;

        float d_front = __shfl(dsv, idx);
        float d_back  = __shfl(dsv, idx + 1);
        float s_front = __shfl(scal, idx);
        float s_back  = __shfl(scal, idx + 1);

        bool mi = (s_front >= l) && (l >= s_back);
        float sd = s_front - s_back;
        bool vd = fabsf(sd) > EPSf;
        bool ms = mi && vd;
        float d_sec = ((l - s_back) * d_front + (s_front - l) * d_back) / (vd ? sd : 1.0f);
        float di = ms ? d_sec : d_back;

        mintb[lv] = mi; msec[lv] = ms; dinit[lv] = di;
        if (g == lv) {
            g_dfs = d_front; g_dbs = d_back; g_sfs = s_front; g_sbs = s_back;
            g_dcur = di; g_lr = l;
        }
    }

    // ---- secant refinement: 16 lanes per level, 4 hidden units per lane ----
    // hoist this lane's 4 weight quads (h = sub + 16k, same order as before)
    const int sub = lane & 15;
    float4 sq0 = ab[sub], sq1 = ab[sub + 16], sq2 = ab[sub + 32], sq3 = ab[sub + 48];

#pragma unroll
    for (int it = 0; it < SECANT_STEPS; ++it) {
        float mx0 = ox + g_dcur * dx, mx1 = oy + g_dcur * dy, mx2 = oz + g_dcur * dz;
        float mn = sqrtf(mx0 * mx0 + mx1 * mx1 + mx2 * mx2);
        float part;
        {
            float p0 = __builtin_fmaf(g_dcur, sq0.y, sq0.x);
            float p1 = __builtin_fmaf(g_dcur, sq1.y, sq1.x);
            float p2 = __builtin_fmaf(g_dcur, sq2.y, sq2.x);
            float p3 = __builtin_fmaf(g_dcur, sq3.y, sq3.x);
            part = fast_tanh(p0) * sq0.z;
            part = __builtin_fmaf(fast_tanh(p1), sq1.z, part);
            part = __builtin_fmaf(fast_tanh(p2), sq2.z, part);
            part = __builtin_fmaf(fast_tanh(p3), sq3.z, part);
        }
#pragma unroll
        for (int m = 1; m < 16; m <<= 1) part += __shfl_xor(part, m, 16);
        float s_mid = part + b2v + (R0f - mn);
        bool mv = mn < R_SPHEREf;
        bool upf = (s_mid > g_lr) && mv;
        bool upb = (s_mid < g_lr) && mv;
        if (upf) { g_dfs = g_dcur; g_sfs = s_mid; }
        if (upb) { g_dbs = g_dcur; g_sbs = s_mid; }
        float sd2 = g_sfs - g_sbs;
        bool ok = fabsf(sd2) > EPSf;
        if (ok) g_dcur = ((g_lr - g_sbs) * g_dfs + (g_sfs - g_lr) * g_dbs) / sd2;
    }

    // gather per-level results onto every lane
    float v0, v1, v2, v3;
    {
        float dc0 = __shfl(g_dcur, 0);
        float dc1 = __shfl(g_dcur, 16);
        float dc2 = __shfl(g_dcur, 32);
        float dc3 = __shfl(g_dcur, 48);
        v0 = msec[0] ? dc0 : dinit[0];
        v1 = msec[1] ? dc1 : dinit[1];
        v2 = msec[2] ? dc2 : dinit[2];
        v3 = msec[3] ? dc3 : dinit[3];
    }
    int m0 = mintb[0], m1 = mintb[1], m2 = mintb[2], m3 = mintb[3];
    int i0 = 0, i1 = 1, i2 = 2, i3 = 3;

    // stable sort of 4 by (value, original index) — 5-comparator network
#define CSWAP(va, ia, ma, vb, ib, mb)                                    \
    { bool sw = (vb < va) || (vb == va && ib < ia);                      \
      if (sw) { float tv = va; va = vb; vb = tv;                         \
                int ti = ia; ia = ib; ib = ti;                           \
                int tm = ma; ma = mb; mb = tm; } }
    CSWAP(v0, i0, m0, v1, i1, m1);
    CSWAP(v2, i2, m2, v3, i3, m3);
    CSWAP(v0, i0, m0, v2, i2, m2);
    CSWAP(v1, i1, m1, v3, i3, m3);
    CSWAP(v1, i1, m1, v2, i2, m2);
#undef CSWAP

    const long long NL = (long long)N * Lc;
    if (lane < Lc) {
        float dv = (lane == 0) ? v0 : (lane == 1) ? v1 : (lane == 2) ? v2 : v3;
        out[(long long)r * Lc + lane] = mask_bound ? dv : 0.0f;
    } else if (lane < 2 * Lc) {
        int k = lane - Lc;
        int mm = (k == 0) ? m0 : (k == 1) ? m1 : (k == 2) ? m2 : m3;
        out[NL + (long long)r * Lc + k] = (mm && mask_bound) ? 1.0f : 0.0f;
    }
}

extern "C" void kernel_launch(void* const* d_in, const int* in_sizes, int n_in,
                              void* d_out, int out_size, void* d_ws, size_t ws_size,
                              hipStream_t stream) {
    const float* rays_o = (const float*)d_in[0];
    const float* rays_d = (const float*)d_in[1];
    const float* levels = (const float*)d_in[2];
    const float* W1 = (const float*)d_in[3];
    const float* b1 = (const float*)d_in[4];
    const float* W2 = (const float*)d_in[5];
    const float* b2 = (const float*)d_in[6];
    float* out = (float*)d_out;

    const int N = in_sizes[0] / 3;          // B*R rays
    const int blocks = (N + 3) / 4;         // 4 waves (rays) per 256-thread block
    manifold_render_kernel<<<blocks, 256, 0, stream>>>(
        rays_o, rays_d, levels, W1, b1, W2, b2, out, N);
}

// Round 5
// 130.293 us; speedup vs baseline: 1.3898x; 1.0963x over previous
//
#include <hip/hip_runtime.h>
#include <cstdint>

#define R_SPHEREf 3.0f
#define NEARf 0.0f
#define FARf 100.0f
#define SECANT_STEPS 4
#define EPSf 1e-4f
#define R0f 1.0f
#define Hh 64
#define Lc 4
#define Sn 64

// tanh via: w2*tanh(x) = w2 - 2*w2 / (exp2(C*x)+1),  C = 2*log2(e).
// C is pre-folded into the per-ray linearization (A2,B2), the -2*w2 into
// m2w2, and the Sum(w2) constant into sbase. Per hidden unit the core is
// fma / v_exp_f32 / add / v_rcp_f32 / fma  (5 instrs). Saturation is exact:
// exp2->inf => rcp->0 (tanh=+1), exp2->0 => r=1 (tanh=-1). No NaN path.
#define C_HI 2.88539004325866699f   // float-nearest 2*log2(e)
#define C_LO 3.8519227871e-08f      // residual for fma correction

__global__ __launch_bounds__(256) void manifold_render_kernel(
    const float* __restrict__ rays_o, const float* __restrict__ rays_d,
    const float* __restrict__ levels, const float* __restrict__ W1,
    const float* __restrict__ b1, const float* __restrict__ W2,
    const float* __restrict__ b2, float* __restrict__ out, int N)
{
    // per-wave {A2_h, B2_h, -2*w2_h, 0} quads: y_h(t) = A2_h + t*B2_h
    __shared__ float4 abq[4][Hh];

    const int tid = threadIdx.x;
    const int wave = tid >> 6;
    const int lane = tid & 63;
    const int r = blockIdx.x * 4 + wave;
    const bool ray_ok = (r < N);

    const float b2v = b2[0];
    float lvl[Lc];
#pragma unroll
    for (int j = 0; j < Lc; ++j) lvl[j] = levels[j];

    float ox = 0.f, oy = 0.f, oz = 0.f, dx = 0.f, dy = 0.f, dz = 1.f;
    if (ray_ok) {
        ox = rays_o[3 * r]; oy = rays_o[3 * r + 1]; oz = rays_o[3 * r + 2];
        dx = rays_d[3 * r]; dy = rays_d[3 * r + 1]; dz = rays_d[3 * r + 2];
    }

    // per-ray linearization, lane h = lane; fold C into A,B; fold -2 into w2
    float w2lane;
    {
        const float w1x = W1[lane], w1y = W1[Hh + lane], w1z = W1[2 * Hh + lane];
        w2lane = W2[lane];
        const float Ah = __builtin_fmaf(oz, w1z, __builtin_fmaf(oy, w1y,
                         __builtin_fmaf(ox, w1x, b1[lane])));
        const float Bh = __builtin_fmaf(dz, w1z, __builtin_fmaf(dy, w1y, dx * w1x));
        const float A2 = __builtin_fmaf(Ah, C_LO, Ah * C_HI);
        const float B2 = __builtin_fmaf(Bh, C_LO, Bh * C_HI);
        abq[wave][lane] = make_float4(A2, B2, -2.0f * w2lane, 0.0f);
    }
    // W2SUM: butterfly sum of w2 across the wave (ray-independent constant)
    float w2sum = w2lane;
#pragma unroll
    for (int m = 1; m < 64; m <<= 1) w2sum += __shfl_xor(w2sum, m);
    const float sbase = w2sum + b2v + R0f;   // added after the -2*w2*r sum

    __syncthreads();
    if (!ray_ok) return;

    // sphere bounds
    const float bq = ox * dx + oy * dy + oz * dz;
    const float cq = ox * ox + oy * oy + oz * oz - R_SPHEREf * R_SPHEREf;
    const float disc = bq * bq - cq;
    const bool hit = disc > 0.0f;
    const float sq = sqrtf(hit ? disc : 1.0f);
    const float d_near = fmaxf(-bq - sq, NEARf);
    const float d_far  = fminf(-bq + sq, FARf);
    const bool mask_bound = hit && (d_near < d_far);

    // ---- sampling: lane = sample index ----
    const float t = (float)lane / (float)(Sn - 1);
    const float dsv = d_near * (1.0f - t) + d_far * t;
    const float x0 = ox + dx * dsv, x1 = oy + dy * dsv, x2 = oz + dz * dsv;
    const float nrm = sqrtf(x0 * x0 + x1 * x1 + x2 * x2);

    const float4* __restrict__ ab = &abq[wave][0];
    float acc = 0.0f;
#pragma unroll
    for (int h = 0; h < Hh; ++h) {
        const float4 q = ab[h];
        const float y = __builtin_fmaf(dsv, q.y, q.x);
        const float e = __builtin_amdgcn_exp2f(y);
        const float r1 = __builtin_amdgcn_rcpf(e + 1.0f);
        acc = __builtin_fmaf(q.z, r1, acc);
    }
    const float scal = (acc + sbase) - nrm;
    const bool valid = nrm < R_SPHEREf;

    // neighbors (back sample of interval at lane j is sample j+1)
    const float scb = __shfl_down(scal, 1);
    const int validn = __shfl_down((int)valid, 1);
    const bool is_int = lane < (Sn - 1);

    // ind_lowest: first-occurrence argmin of sc_b over intervals
    float keyv = is_int ? scb : INFINITY;
    int keyi = lane;
#pragma unroll
    for (int m = 1; m < 64; m <<= 1) {
        float ov = __shfl_xor(keyv, m);
        int oi = __shfl_xor(keyi, m);
        if (ov < keyv || (ov == keyv && oi < keyi)) { keyv = ov; keyi = oi; }
    }
    const int ind_lowest = keyi;

    const bool inint_base = is_int && valid && (validn != 0);

    // per-level interval pick + secant init (uniform over all lanes)
    bool mintb[Lc], msec[Lc];
    float dinit[Lc];
    float g_dfs = 0.f, g_dbs = 0.f, g_sfs = 0.f, g_sbs = 0.f, g_dcur = 0.f, g_lr = 0.f;
    const int g = lane >> 4;

#pragma unroll
    for (int lv = 0; lv < Lc; ++lv) {
        const float l = lvl[lv];
        unsigned long long bP = __ballot(is_int && (scb < l));
        unsigned long long bZ = __ballot(is_int && (scb == l));
        unsigned long long bI = __ballot(inint_base && (scal >= l) && (l >= scb));
        // argmax of sign(l - sc_b)*(63-j): first j with sc_b<l, else first ==, else 62
        int ind_closest = bP ? __builtin_ctzll(bP)
                             : (bZ ? __builtin_ctzll(bZ) : (Sn - 2));
        bool mask_surface = (bI != 0ULL);
        int idx = mask_surface ? ind_closest : ind_lowest;

        float d_front = __shfl(dsv, idx);
        float d_back  = __shfl(dsv, idx + 1);
        float s_front = __shfl(scal, idx);
        float s_back  = __shfl(scal, idx + 1);

        bool mi = (s_front >= l) && (l >= s_back);
        float sd = s_front - s_back;
        bool vd = fabsf(sd) > EPSf;
        bool ms = mi && vd;
        float d_sec = ((l - s_back) * d_front + (s_front - l) * d_back) / (vd ? sd : 1.0f);
        float di = ms ? d_sec : d_back;

        mintb[lv] = mi; msec[lv] = ms; dinit[lv] = di;
        if (g == lv) {
            g_dfs = d_front; g_dbs = d_back; g_sfs = s_front; g_sbs = s_back;
            g_dcur = di; g_lr = l;
        }
    }

    // ---- secant refinement: 16 lanes per level, 4 hidden units per lane ----
    const int sub = lane & 15;
    float4 sq0 = ab[sub], sq1 = ab[sub + 16], sq2 = ab[sub + 32], sq3 = ab[sub + 48];

#pragma unroll
    for (int it = 0; it < SECANT_STEPS; ++it) {
        float mx0 = ox + g_dcur * dx, mx1 = oy + g_dcur * dy, mx2 = oz + g_dcur * dz;
        float mn = sqrtf(mx0 * mx0 + mx1 * mx1 + mx2 * mx2);
        float part;
        {
            float y0 = __builtin_fmaf(g_dcur, sq0.y, sq0.x);
            float y1 = __builtin_fmaf(g_dcur, sq1.y, sq1.x);
            float y2 = __builtin_fmaf(g_dcur, sq2.y, sq2.x);
            float y3 = __builtin_fmaf(g_dcur, sq3.y, sq3.x);
            float r0 = __builtin_amdgcn_rcpf(__builtin_amdgcn_exp2f(y0) + 1.0f);
            float r1 = __builtin_amdgcn_rcpf(__builtin_amdgcn_exp2f(y1) + 1.0f);
            float r2 = __builtin_amdgcn_rcpf(__builtin_amdgcn_exp2f(y2) + 1.0f);
            float r3 = __builtin_amdgcn_rcpf(__builtin_amdgcn_exp2f(y3) + 1.0f);
            part = sq0.z * r0;
            part = __builtin_fmaf(sq1.z, r1, part);
            part = __builtin_fmaf(sq2.z, r2, part);
            part = __builtin_fmaf(sq3.z, r3, part);
        }
#pragma unroll
        for (int m = 1; m < 16; m <<= 1) part += __shfl_xor(part, m, 16);
        float s_mid = (part + sbase) - mn;
        bool mv = mn < R_SPHEREf;
        bool upf = (s_mid > g_lr) && mv;
        bool upb = (s_mid < g_lr) && mv;
        if (upf) { g_dfs = g_dcur; g_sfs = s_mid; }
        if (upb) { g_dbs = g_dcur; g_sbs = s_mid; }
        float sd2 = g_sfs - g_sbs;
        bool ok = fabsf(sd2) > EPSf;
        if (ok) g_dcur = ((g_lr - g_sbs) * g_dfs + (g_sfs - g_lr) * g_dbs) / sd2;
    }

    // gather per-level results onto every lane
    float v0, v1, v2, v3;
    {
        float dc0 = __shfl(g_dcur, 0);
        float dc1 = __shfl(g_dcur, 16);
        float dc2 = __shfl(g_dcur, 32);
        float dc3 = __shfl(g_dcur, 48);
        v0 = msec[0] ? dc0 : dinit[0];
        v1 = msec[1] ? dc1 : dinit[1];
        v2 = msec[2] ? dc2 : dinit[2];
        v3 = msec[3] ? dc3 : dinit[3];
    }
    int m0 = mintb[0], m1 = mintb[1], m2 = mintb[2], m3 = mintb[3];
    int i0 = 0, i1 = 1, i2 = 2, i3 = 3;

    // stable sort of 4 by (value, original index) — 5-comparator network
#define CSWAP(va, ia, ma, vb, ib, mb)                                    \
    { bool sw = (vb < va) || (vb == va && ib < ia);                      \
      if (sw) { float tv = va; va = vb; vb = tv;                         \
                int ti = ia; ia = ib; ib = ti;                           \
                int tm = ma; ma = mb; mb = tm; } }
    CSWAP(v0, i0, m0, v1, i1, m1);
    CSWAP(v2, i2, m2, v3, i3, m3);
    CSWAP(v0, i0, m0, v2, i2, m2);
    CSWAP(v1, i1, m1, v3, i3, m3);
    CSWAP(v1, i1, m1, v2, i2, m2);
#undef CSWAP

    const long long NL = (long long)N * Lc;
    if (lane < Lc) {
        float dv = (lane == 0) ? v0 : (lane == 1) ? v1 : (lane == 2) ? v2 : v3;
        out[(long long)r * Lc + lane] = mask_bound ? dv : 0.0f;
    } else if (lane < 2 * Lc) {
        int k = lane - Lc;
        int mm = (k == 0) ? m0 : (k == 1) ? m1 : (k == 2) ? m2 : m3;
        out[NL + (long long)r * Lc + k] = (mm && mask_bound) ? 1.0f : 0.0f;
    }
}

extern "C" void kernel_launch(void* const* d_in, const int* in_sizes, int n_in,
                              void* d_out, int out_size, void* d_ws, size_t ws_size,
                              hipStream_t stream) {
    const float* rays_o = (const float*)d_in[0];
    const float* rays_d = (const float*)d_in[1];
    const float* levels = (const float*)d_in[2];
    const float* W1 = (const float*)d_in[3];
    const float* b1 = (const float*)d_in[4];
    const float* W2 = (const float*)d_in[5];
    const float* b2 = (const float*)d_in[6];
    float* out = (float*)d_out;

    const int N = in_sizes[0] / 3;          // B*R rays
    const int blocks = (N + 3) / 4;         // 4 waves (rays) per 256-thread block
    manifold_render_kernel<<<blocks, 256, 0, stream>>>(
        rays_o, rays_d, levels, W1, b1, W2, b2, out, N);
}